// Round 1
// baseline (1311.537 us; speedup 1.0000x reference)
//
#include <hip/hip_runtime.h>

typedef unsigned long long u64;
typedef unsigned int u32;

#define R_TOT 159882
#define NPAD 8192
#define K_TOT 4507
#define CSTR 4608
#define POST 1000
#define IMG_SZ 800.0f
#define NMS_TH 0.7f
#define BBOX_CLIP 4.135166556742356f

__device__ __forceinline__ float fadd_(float a, float b){ return __fadd_rn(a,b); }
__device__ __forceinline__ float fsub_(float a, float b){ return __fsub_rn(a,b); }
__device__ __forceinline__ float fmul_(float a, float b){ return __fmul_rn(a,b); }

__device__ __forceinline__ int level_of(int r){
  return r < 120000 ? 0 : r < 150000 ? 1 : r < 157500 ? 2 : r < 159375 ? 3 : 4;
}

// key = (level asc | value desc | idx asc) -> ascending sort == reference concat order
__device__ __forceinline__ u64 make_key(float f, int lvl, int idx){
  u32 u = __float_as_uint(f);
  u32 mu = (u & 0x80000000u) ? ~u : (u | 0x80000000u); // monotonic: larger f -> larger mu
  return ((u64)lvl << 56) | ((u64)(~mu) << 24) | (u32)idx;
}

__global__ void k_init(u64* cand, int* cnt, unsigned char* kg){
  int t = blockIdx.x * blockDim.x + threadIdx.x;
  int nt = gridDim.x * blockDim.x;
  for (int i = t; i < 2*NPAD; i += nt) cand[i] = ~0ull;
  for (int i = t; i < 2*CSTR; i += nt) kg[i] = 0;
  if (t < 2) cnt[t] = 0;
}

// exact radix-select of the k-th smallest 64-bit key per (img, level)
__global__ __launch_bounds__(1024) void k_select(const float* __restrict__ obj, u64* Tsel){
  const int LOFF[5] = {0, 120000, 150000, 157500, 159375};
  const int LLEN[5] = {120000, 30000, 7500, 1875, 507};
  const int LK[5]   = {1000, 1000, 1000, 1000, 507};
  int img = blockIdx.x / 5, lvl = blockIdx.x % 5;
  int s0 = LOFF[lvl], n = LLEN[lvl];
  const float* p = obj + img * R_TOT;
  __shared__ int hist[16*256];
  __shared__ u64 sh_pref, sh_mask;
  __shared__ int sh_rem;
  int tid = threadIdx.x, wid = tid >> 6;
  if (tid == 0){ sh_pref = ((u64)lvl) << 56; sh_mask = 0xFF00000000000000ull; sh_rem = LK[lvl]; }
  __syncthreads();
  for (int pass = 0; pass < 7; pass++){
    int shift = 48 - 8*pass;
    for (int b = tid; b < 16*256; b += 1024) hist[b] = 0;
    __syncthreads();
    u64 pref = sh_pref, msk = sh_mask;
    for (int e = tid; e < n; e += 1024){
      u64 key = make_key(p[s0 + e], lvl, s0 + e);
      if ((key & msk) == pref) atomicAdd(&hist[(wid << 8) + (int)((key >> shift) & 255)], 1);
    }
    __syncthreads();
    if (tid < 256){ int s = 0; for (int w = 0; w < 16; w++) s += hist[(w << 8) + tid]; hist[tid] = s; }
    __syncthreads();
    if (tid == 0){
      int rem = sh_rem, cum = 0, d = 0;
      for (int b = 0; b < 256; b++){ int c = hist[b]; if (cum + c >= rem){ d = b; break; } cum += c; }
      sh_rem = rem - cum;
      sh_pref = pref | ((u64)d << shift);
      sh_mask = msk | (0xFFull << shift);
    }
    __syncthreads();
  }
  if (tid == 0) Tsel[blockIdx.x] = sh_pref;
}

__global__ void k_gather(const float* __restrict__ obj, const u64* __restrict__ Tsel,
                         u64* cand, int* cnt){
  int t = blockIdx.x * blockDim.x + threadIdx.x;
  if (t >= 2*R_TOT) return;
  int img = t / R_TOT, r = t - img * R_TOT;
  int lvl = level_of(r);
  u64 key = make_key(obj[t], lvl, r);
  if (key <= Tsel[img*5 + lvl]){
    int pos = atomicAdd(&cnt[img], 1);
    cand[img*NPAD + pos] = key;
  }
}

__device__ void bitonic_sort(u64* s){
  for (int k = 2; k <= NPAD; k <<= 1){
    for (int j = k >> 1; j > 0; j >>= 1){
      __syncthreads();
      for (int i = threadIdx.x; i < NPAD; i += blockDim.x){
        int ixj = i ^ j;
        if (ixj > i){
          u64 a = s[i], b = s[ixj];
          bool up = (i & k) == 0;
          if ((a > b) == up){ s[i] = b; s[ixj] = a; }
        }
      }
    }
  }
  __syncthreads();
}

__global__ __launch_bounds__(1024) void k_sortA(const u64* __restrict__ cand, u32* sidx){
  __shared__ u64 sh[NPAD];
  int img = blockIdx.x;
  for (int i = threadIdx.x; i < NPAD; i += 1024) sh[i] = cand[img*NPAD + i];
  bitonic_sort(sh);
  for (int p = threadIdx.x; p < K_TOT; p += 1024) sidx[img*CSTR + p] = (u32)(sh[p] & 0xFFFFFFu);
}

__global__ void k_decode(const float* __restrict__ obj, const float4* __restrict__ deltas,
                         const float4* __restrict__ anchors, const u32* __restrict__ sidx,
                         u64* cand, float4* boxv, float* scv, int* meta){
  int t = blockIdx.x * blockDim.x + threadIdx.x;
  if (t >= 2*NPAD) return;
  int img = t >> 13, p = t & (NPAD - 1);
  if (p >= K_TOT){ cand[t] = ~0ull; return; }
  int idx = (int)sidx[img*CSTR + p];
  int lvl = level_of(idx);
  float4 a = anchors[idx];
  float4 d = deltas[img*R_TOT + idx];
  float o = obj[img*R_TOT + idx];
  float wa = fsub_(a.z, a.x), ha = fsub_(a.w, a.y);
  float cxa = fadd_(a.x, fmul_(0.5f, wa)), cya = fadd_(a.y, fmul_(0.5f, ha));
  float dw = fminf(d.z, BBOX_CLIP), dh = fminf(d.w, BBOX_CLIP);
  float cx = fadd_(fmul_(d.x, wa), cxa), cy = fadd_(fmul_(d.y, ha), cya);
  float w  = fmul_(expf(dw), wa),        h  = fmul_(expf(dh), ha);
  float x1 = fsub_(cx, fmul_(0.5f, w)), y1 = fsub_(cy, fmul_(0.5f, h));
  float x2 = fadd_(cx, fmul_(0.5f, w)), y2 = fadd_(cy, fmul_(0.5f, h));
  x1 = fminf(fmaxf(x1, 0.0f), IMG_SZ); y1 = fminf(fmaxf(y1, 0.0f), IMG_SZ);
  x2 = fminf(fmaxf(x2, 0.0f), IMG_SZ); y2 = fminf(fmaxf(y2, 0.0f), IMG_SZ);
  bool valid = (fsub_(x2, x1) >= 1e-3f) && (fsub_(y2, y1) >= 1e-3f);
  float e = expf(-o);
  float sig = __fdiv_rn(1.0f, fadd_(1.0f, e));
  float s = valid ? sig : -1.0f;
  u32 sb = __float_as_uint(s);
  u32 ms = (sb & 0x80000000u) ? ~sb : (sb | 0x80000000u);
  cand[t] = ((u64)(~ms) << 32) | (u32)p;   // (score desc, concat pos asc) = stable argsort(-s)
  boxv[img*CSTR + p] = make_float4(x1, y1, x2, y2);
  scv[img*CSTR + p] = sig;
  meta[img*CSTR + p] = lvl | (valid ? 256 : 0);
}

__global__ __launch_bounds__(1024) void k_sortB(const u64* __restrict__ cand, u32* ordA){
  __shared__ u64 sh[NPAD];
  int img = blockIdx.x;
  for (int i = threadIdx.x; i < NPAD; i += 1024) sh[i] = cand[img*NPAD + i];
  bitonic_sort(sh);
  for (int s = threadIdx.x; s < K_TOT; s += 1024) ordA[img*CSTR + s] = (u32)(sh[s] & 0xFFFFFFFFull);
}

// greedy NMS per (img, level); cross-level IoU is exactly 0 by the 801*lvl offset trick
__global__ __launch_bounds__(256) void k_nms(const u32* __restrict__ ordA, const int* __restrict__ meta,
                                             const float4* __restrict__ boxv, unsigned char* kg){
  int img = blockIdx.x / 5, lvl = blockIdx.x % 5;
  __shared__ float mx1[1024], my1[1024], mx2[1024], my2[1024];
  __shared__ int msl[1024];
  __shared__ unsigned char sup[1024];
  __shared__ int m_sh;
  int tid = threadIdx.x;
  if (tid < 64){
    int cnt = 0;
    float off = lvl * 801.0f;
    for (int base = 0; base < K_TOT; base += 64){
      int s = base + tid;
      bool match = false; float4 b = make_float4(0,0,0,0);
      if (s < K_TOT){
        int p = (int)ordA[img*CSTR + s];
        int mt = meta[img*CSTR + p];
        if ((mt & 255) == lvl && (mt & 256)){ match = true; b = boxv[img*CSTR + p]; }
      }
      u64 mask = __ballot(match);
      int before = __popcll(mask & ((1ull << tid) - 1ull));
      if (match){
        int pos = cnt + before;
        mx1[pos] = fadd_(b.x, off); my1[pos] = fadd_(b.y, off);
        mx2[pos] = fadd_(b.z, off); my2[pos] = fadd_(b.w, off);
        msl[pos] = s;
      }
      cnt += __popcll(mask);
    }
    if (tid == 0) m_sh = cnt;
  }
  for (int i = tid; i < 1024; i += 256) sup[i] = 0;
  __syncthreads();
  int m = m_sh;
  int i = 0;
  while (true){
    while (i < m && sup[i]) i++;     // uniform: all threads see identical LDS state
    if (i >= m) break;
    if (tid == 0) kg[img*CSTR + msl[i]] = 1;
    float ax1 = mx1[i], ay1 = my1[i], ax2 = mx2[i], ay2 = my2[i];
    float areaA = fmul_(fsub_(ax2, ax1), fsub_(ay2, ay1));
    for (int j = i + 1 + tid; j < m; j += 256){
      if (!sup[j]){
        float bx1 = mx1[j], by1 = my1[j], bx2 = mx2[j], by2 = my2[j];
        float ltx = fmaxf(ax1, bx1), lty = fmaxf(ay1, by1);
        float rbx = fminf(ax2, bx2), rby = fminf(ay2, by2);
        float wx = fmaxf(fsub_(rbx, ltx), 0.0f), wy = fmaxf(fsub_(rby, lty), 0.0f);
        float inter = fmul_(wx, wy);
        float areaB = fmul_(fsub_(bx2, bx1), fsub_(by2, by1));
        float den = fadd_(fsub_(fadd_(areaA, areaB), inter), 1e-9f);
        if (__fdiv_rn(inter, den) > NMS_TH) sup[j] = 1;
      }
    }
    i++;
    __syncthreads();
  }
}

__global__ __launch_bounds__(64) void k_output(const unsigned char* __restrict__ kg,
                                               const u32* __restrict__ ordA,
                                               const float4* __restrict__ boxv,
                                               const float* __restrict__ scv, float* out){
  int img = blockIdx.x, tid = threadIdx.x;
  for (int t = tid; t < POST*4; t += 64) out[img*POST*4 + t] = 0.0f;
  for (int t = tid; t < POST; t += 64) out[2*POST*4 + img*POST + t] = -1.0f;
  __syncthreads();
  const int CH = (K_TOT + 63) / 64;  // 71
  int lo = tid * CH, hi = min(lo + CH, K_TOT);
  int c = 0;
  for (int s = lo; s < hi; s++) c += kg[img*CSTR + s];
  int x = c;
  for (int d = 1; d < 64; d <<= 1){ int y = __shfl_up(x, d); if (tid >= d) x += y; }
  int rank = x - c;  // exclusive prefix = cumsum-1 for kept
  for (int s = lo; s < hi; s++){
    if (kg[img*CSTR + s]){
      if (rank < POST){
        int p = (int)ordA[img*CSTR + s];
        float4 b = boxv[img*CSTR + p];
        out[img*POST*4 + rank*4 + 0] = b.x;
        out[img*POST*4 + rank*4 + 1] = b.y;
        out[img*POST*4 + rank*4 + 2] = b.z;
        out[img*POST*4 + rank*4 + 3] = b.w;
        out[2*POST*4 + img*POST + rank] = scv[img*CSTR + p];
      }
      rank++;
    }
  }
}

extern "C" void kernel_launch(void* const* d_in, const int* in_sizes, int n_in,
                              void* d_out, int out_size, void* d_ws, size_t ws_size,
                              hipStream_t stream){
  (void)in_sizes; (void)n_in; (void)out_size; (void)ws_size;
  const float*  obj     = (const float*)d_in[0];
  const float4* deltas  = (const float4*)d_in[1];
  const float4* anchors = (const float4*)d_in[2];
  float* out = (float*)d_out;
  char* ws = (char*)d_ws;
  // workspace layout (total ~435 KB)
  u64* cand = (u64*)(ws + 0);              // 2*8192 u64
  u64* Tsel = (u64*)(ws + 131072);         // 10 u64
  int* cnt  = (int*)(ws + 131200);         // 2 int
  u32* sidx = (u32*)(ws + 131328);         // 2*4608 u32
  u32* ordA = (u32*)(ws + 168192);         // 2*4608 u32
  float4* boxv = (float4*)(ws + 205056);   // 2*4608 float4
  float* scv   = (float*)(ws + 352512);    // 2*4608 float
  int* meta    = (int*)(ws + 389376);      // 2*4608 int
  unsigned char* kg = (unsigned char*)(ws + 426240); // 2*4608 bytes

  k_init  <<<64, 256, 0, stream>>>(cand, cnt, kg);
  k_select<<<10, 1024, 0, stream>>>(obj, Tsel);
  k_gather<<<(2*R_TOT + 255)/256, 256, 0, stream>>>(obj, Tsel, cand, cnt);
  k_sortA <<<2, 1024, 0, stream>>>(cand, sidx);
  k_decode<<<(2*NPAD + 255)/256, 256, 0, stream>>>(obj, deltas, anchors, sidx, cand, boxv, scv, meta);
  k_sortB <<<2, 1024, 0, stream>>>(cand, ordA);
  k_nms   <<<10, 256, 0, stream>>>(ordA, meta, boxv, kg);
  k_output<<<2, 64, 0, stream>>>(kg, ordA, boxv, scv, out);
}

// Round 2
// 914.337 us; speedup vs baseline: 1.4344x; 1.4344x over previous
//
#include <hip/hip_runtime.h>

typedef unsigned long long u64;
typedef unsigned int u32;

#define R_TOT 159882
#define NPAD 8192
#define K_TOT 4507
#define CSTR 4608
#define POST 1000
#define IMG_SZ 800.0f
#define NMS_TH 0.7f
#define BBOX_CLIP 4.135166556742356f

__device__ __forceinline__ float fadd_(float a, float b){ return __fadd_rn(a,b); }
__device__ __forceinline__ float fsub_(float a, float b){ return __fsub_rn(a,b); }
__device__ __forceinline__ float fmul_(float a, float b){ return __fmul_rn(a,b); }

__device__ __forceinline__ int level_of(int r){
  return r < 120000 ? 0 : r < 150000 ? 1 : r < 157500 ? 2 : r < 159375 ? 3 : 4;
}

// key = (level asc | value desc | idx asc) -> ascending sort == reference concat order
__device__ __forceinline__ u64 make_key(float f, int lvl, int idx){
  u32 u = __float_as_uint(f);
  u32 mu = (u & 0x80000000u) ? ~u : (u | 0x80000000u); // monotonic: larger f -> larger mu
  return ((u64)lvl << 56) | ((u64)(~mu) << 24) | (u32)idx;
}

__global__ void k_init(u64* cand, int* cnt, unsigned char* kg, u64* maskg){
  int t = blockIdx.x * blockDim.x + threadIdx.x;
  int nt = gridDim.x * blockDim.x;
  for (int i = t; i < 2*NPAD; i += nt) cand[i] = ~0ull;
  for (int i = t; i < 2*CSTR; i += nt) kg[i] = 0;
  for (int i = t; i < 10*1024*16; i += nt) maskg[i] = 0;
  if (t < 2) cnt[t] = 0;
}

// exact radix-select of the k-th smallest 64-bit key per (img, level)
__global__ __launch_bounds__(1024) void k_select(const float* __restrict__ obj, u64* Tsel){
  const int LOFF[5] = {0, 120000, 150000, 157500, 159375};
  const int LLEN[5] = {120000, 30000, 7500, 1875, 507};
  const int LK[5]   = {1000, 1000, 1000, 1000, 507};
  int img = blockIdx.x / 5, lvl = blockIdx.x % 5;
  int s0 = LOFF[lvl], n = LLEN[lvl];
  const float* p = obj + img * R_TOT;
  __shared__ int hist[16*256];
  __shared__ u64 sh_pref, sh_mask;
  __shared__ int sh_rem;
  int tid = threadIdx.x, wid = tid >> 6;
  if (tid == 0){ sh_pref = ((u64)lvl) << 56; sh_mask = 0xFF00000000000000ull; sh_rem = LK[lvl]; }
  __syncthreads();
  for (int pass = 0; pass < 7; pass++){
    int shift = 48 - 8*pass;
    for (int b = tid; b < 16*256; b += 1024) hist[b] = 0;
    __syncthreads();
    u64 pref = sh_pref, msk = sh_mask;
    for (int e = tid; e < n; e += 1024){
      u64 key = make_key(p[s0 + e], lvl, s0 + e);
      if ((key & msk) == pref) atomicAdd(&hist[(wid << 8) + (int)((key >> shift) & 255)], 1);
    }
    __syncthreads();
    if (tid < 256){ int s = 0; for (int w = 0; w < 16; w++) s += hist[(w << 8) + tid]; hist[tid] = s; }
    __syncthreads();
    if (tid == 0){
      int rem = sh_rem, cum = 0, d = 0;
      for (int b = 0; b < 256; b++){ int c = hist[b]; if (cum + c >= rem){ d = b; break; } cum += c; }
      sh_rem = rem - cum;
      sh_pref = pref | ((u64)d << shift);
      sh_mask = msk | (0xFFull << shift);
    }
    __syncthreads();
  }
  if (tid == 0) Tsel[blockIdx.x] = sh_pref;
}

__global__ void k_gather(const float* __restrict__ obj, const u64* __restrict__ Tsel,
                         u64* cand, int* cnt){
  int t = blockIdx.x * blockDim.x + threadIdx.x;
  if (t >= 2*R_TOT) return;
  int img = t / R_TOT, r = t - img * R_TOT;
  int lvl = level_of(r);
  u64 key = make_key(obj[t], lvl, r);
  if (key <= Tsel[img*5 + lvl]){
    int pos = atomicAdd(&cnt[img], 1);
    cand[img*NPAD + pos] = key;
  }
}

__device__ void bitonic_sort(u64* s){
  for (int k = 2; k <= NPAD; k <<= 1){
    for (int j = k >> 1; j > 0; j >>= 1){
      __syncthreads();
      for (int i = threadIdx.x; i < NPAD; i += blockDim.x){
        int ixj = i ^ j;
        if (ixj > i){
          u64 a = s[i], b = s[ixj];
          bool up = (i & k) == 0;
          if ((a > b) == up){ s[i] = b; s[ixj] = a; }
        }
      }
    }
  }
  __syncthreads();
}

__global__ __launch_bounds__(1024) void k_sortA(const u64* __restrict__ cand, u32* sidx){
  __shared__ u64 sh[NPAD];
  int img = blockIdx.x;
  for (int i = threadIdx.x; i < NPAD; i += 1024) sh[i] = cand[img*NPAD + i];
  bitonic_sort(sh);
  for (int p = threadIdx.x; p < K_TOT; p += 1024) sidx[img*CSTR + p] = (u32)(sh[p] & 0xFFFFFFu);
}

__global__ void k_decode(const float* __restrict__ obj, const float4* __restrict__ deltas,
                         const float4* __restrict__ anchors, const u32* __restrict__ sidx,
                         u64* cand, float4* boxv, float* scv, int* meta){
  int t = blockIdx.x * blockDim.x + threadIdx.x;
  if (t >= 2*NPAD) return;
  int img = t >> 13, p = t & (NPAD - 1);
  if (p >= K_TOT){ cand[t] = ~0ull; return; }
  int idx = (int)sidx[img*CSTR + p];
  int lvl = level_of(idx);
  float4 a = anchors[idx];
  float4 d = deltas[img*R_TOT + idx];
  float o = obj[img*R_TOT + idx];
  float wa = fsub_(a.z, a.x), ha = fsub_(a.w, a.y);
  float cxa = fadd_(a.x, fmul_(0.5f, wa)), cya = fadd_(a.y, fmul_(0.5f, ha));
  float dw = fminf(d.z, BBOX_CLIP), dh = fminf(d.w, BBOX_CLIP);
  float cx = fadd_(fmul_(d.x, wa), cxa), cy = fadd_(fmul_(d.y, ha), cya);
  float w  = fmul_(expf(dw), wa),        h  = fmul_(expf(dh), ha);
  float x1 = fsub_(cx, fmul_(0.5f, w)), y1 = fsub_(cy, fmul_(0.5f, h));
  float x2 = fadd_(cx, fmul_(0.5f, w)), y2 = fadd_(cy, fmul_(0.5f, h));
  x1 = fminf(fmaxf(x1, 0.0f), IMG_SZ); y1 = fminf(fmaxf(y1, 0.0f), IMG_SZ);
  x2 = fminf(fmaxf(x2, 0.0f), IMG_SZ); y2 = fminf(fmaxf(y2, 0.0f), IMG_SZ);
  bool valid = (fsub_(x2, x1) >= 1e-3f) && (fsub_(y2, y1) >= 1e-3f);
  float e = expf(-o);
  float sig = __fdiv_rn(1.0f, fadd_(1.0f, e));
  float s = valid ? sig : -1.0f;
  u32 sb = __float_as_uint(s);
  u32 ms = (sb & 0x80000000u) ? ~sb : (sb | 0x80000000u);
  cand[t] = ((u64)(~ms) << 32) | (u32)p;   // (score desc, concat pos asc) = stable argsort(-s)
  boxv[img*CSTR + p] = make_float4(x1, y1, x2, y2);
  scv[img*CSTR + p] = sig;
  meta[img*CSTR + p] = lvl | (valid ? 256 : 0);
}

__global__ __launch_bounds__(1024) void k_sortB(const u64* __restrict__ cand, u32* ordA){
  __shared__ u64 sh[NPAD];
  int img = blockIdx.x;
  for (int i = threadIdx.x; i < NPAD; i += 1024) sh[i] = cand[img*NPAD + i];
  bitonic_sort(sh);
  for (int s = threadIdx.x; s < K_TOT; s += 1024) ordA[img*CSTR + s] = (u32)(sh[s] & 0xFFFFFFFFull);
}

// compact valid boxes of (img,lvl) in score order; apply the 801*lvl offset (same fp ops as before)
__global__ __launch_bounds__(64) void k_nmsprep(const u32* __restrict__ ordA, const int* __restrict__ meta,
                                                const float4* __restrict__ boxv,
                                                float4* nbox, int* nslot, int* nmcnt){
  int img = blockIdx.x / 5, lvl = blockIdx.x % 5;
  int g = blockIdx.x, tid = threadIdx.x;
  int cnt = 0;
  float off = lvl * 801.0f;
  for (int base = 0; base < K_TOT; base += 64){
    int s = base + tid;
    bool match = false; float4 b = make_float4(0,0,0,0);
    if (s < K_TOT){
      int p = (int)ordA[img*CSTR + s];
      int mt = meta[img*CSTR + p];
      if ((mt & 255) == lvl && (mt & 256)){ match = true; b = boxv[img*CSTR + p]; }
    }
    u64 mask = __ballot(match);
    int before = __popcll(mask & ((1ull << tid) - 1ull));
    if (match){
      int pos = cnt + before;
      nbox[g*1024 + pos] = make_float4(fadd_(b.x,off), fadd_(b.y,off), fadd_(b.z,off), fadd_(b.w,off));
      nslot[g*1024 + pos] = s;
    }
    cnt += __popcll(mask);
  }
  if (tid == 0) nmcnt[g] = cnt;
}

// pairwise IoU -> suppression bitmask (bit jj of mask[i][tj] set iff iou(i, tj*64+jj) > TH, j > i)
__global__ __launch_bounds__(64) void k_mask(const float4* __restrict__ nbox,
                                             const int* __restrict__ nmcnt, u64* maskg){
  int g = blockIdx.x, ti = blockIdx.y, tj = blockIdx.z;
  if (tj < ti) return;
  int m = nmcnt[g];
  if (ti*64 >= m || tj*64 >= m) return;
  __shared__ float4 shb[64];
  int t = threadIdx.x;
  int j0 = tj*64;
  if (j0 + t < m) shb[t] = nbox[g*1024 + j0 + t];
  __syncthreads();
  int i = ti*64 + t;
  if (i >= m) return;
  float4 a = nbox[g*1024 + i];
  float areaA = fmul_(fsub_(a.z,a.x), fsub_(a.w,a.y));
  u64 bits = 0;
  int jmax = min(64, m - j0);
  for (int jj = 0; jj < jmax; jj++){
    int j = j0 + jj;
    if (j <= i) continue;
    float4 b = shb[jj];
    float ltx = fmaxf(a.x, b.x), lty = fmaxf(a.y, b.y);
    float rbx = fminf(a.z, b.z), rby = fminf(a.w, b.w);
    float wx = fmaxf(fsub_(rbx, ltx), 0.0f), wy = fmaxf(fsub_(rby, lty), 0.0f);
    float inter = fmul_(wx, wy);
    float areaB = fmul_(fsub_(b.z,b.x), fsub_(b.w,b.y));
    float den = fadd_(fsub_(fadd_(areaA, areaB), inter), 1e-9f);
    if (__fdiv_rn(inter, den) > NMS_TH) bits |= (1ull << jj);
  }
  maskg[(g*1024 + i)*16 + tj] = bits;
}

// greedy reduction over the bitmask: one wave per (img,lvl)
__global__ __launch_bounds__(64) void k_scan(const u64* __restrict__ maskg,
                                             const int* __restrict__ nmcnt,
                                             const int* __restrict__ nslot,
                                             unsigned char* kg){
  int g = blockIdx.x, img = g / 5;
  int m = nmcnt[g];
  int tid = threadIdx.x;
  __shared__ u64 shm[1024];
  u64 remv = 0;
  int nch = (m + 63) >> 6;
  for (int c = 0; c < nch; c++){
    __syncthreads();
    for (int idx = tid; idx < 1024; idx += 64){
      int row = c*64 + (idx >> 4);
      shm[idx] = (row < m) ? maskg[(g*1024 + row)*16 + (idx & 15)] : 0;
    }
    __syncthreads();
    int hi = min(64, m - c*64);
    u64 rw_next = (tid < 16) ? shm[tid] : 0;
    for (int jj = 0; jj < hi; jj++){
      u64 rw = rw_next;
      rw_next = (jj+1 < hi && tid < 16) ? shm[(jj+1)*16 + tid] : 0;
      u64 w = __shfl(remv, c);
      if (!((w >> jj) & 1ull)){
        if (tid == 0) kg[img*CSTR + nslot[g*1024 + c*64 + jj]] = 1;
        remv |= rw;
      }
    }
  }
}

__global__ __launch_bounds__(64) void k_output(const unsigned char* __restrict__ kg,
                                               const u32* __restrict__ ordA,
                                               const float4* __restrict__ boxv,
                                               const float* __restrict__ scv, float* out){
  int img = blockIdx.x, tid = threadIdx.x;
  for (int t = tid; t < POST*4; t += 64) out[img*POST*4 + t] = 0.0f;
  for (int t = tid; t < POST; t += 64) out[2*POST*4 + img*POST + t] = -1.0f;
  __syncthreads();
  const int CH = (K_TOT + 63) / 64;  // 71
  int lo = tid * CH, hi = min(lo + CH, K_TOT);
  int c = 0;
  for (int s = lo; s < hi; s++) c += kg[img*CSTR + s];
  int x = c;
  for (int d = 1; d < 64; d <<= 1){ int y = __shfl_up(x, d); if (tid >= d) x += y; }
  int rank = x - c;  // exclusive prefix = cumsum-1 for kept
  for (int s = lo; s < hi; s++){
    if (kg[img*CSTR + s]){
      if (rank < POST){
        int p = (int)ordA[img*CSTR + s];
        float4 b = boxv[img*CSTR + p];
        out[img*POST*4 + rank*4 + 0] = b.x;
        out[img*POST*4 + rank*4 + 1] = b.y;
        out[img*POST*4 + rank*4 + 2] = b.z;
        out[img*POST*4 + rank*4 + 3] = b.w;
        out[2*POST*4 + img*POST + rank] = scv[img*CSTR + p];
      }
      rank++;
    }
  }
}

extern "C" void kernel_launch(void* const* d_in, const int* in_sizes, int n_in,
                              void* d_out, int out_size, void* d_ws, size_t ws_size,
                              hipStream_t stream){
  (void)in_sizes; (void)n_in; (void)out_size; (void)ws_size;
  const float*  obj     = (const float*)d_in[0];
  const float4* deltas  = (const float4*)d_in[1];
  const float4* anchors = (const float4*)d_in[2];
  float* out = (float*)d_out;
  char* ws = (char*)d_ws;
  // workspace layout (total ~1.95 MB)
  u64* cand = (u64*)(ws + 0);              // 2*8192 u64
  u64* Tsel = (u64*)(ws + 131072);         // 10 u64
  int* cnt  = (int*)(ws + 131200);         // 2 int
  u32* sidx = (u32*)(ws + 131328);         // 2*4608 u32
  u32* ordA = (u32*)(ws + 168192);         // 2*4608 u32
  float4* boxv = (float4*)(ws + 205056);   // 2*4608 float4
  float* scv   = (float*)(ws + 352512);    // 2*4608 float
  int* meta    = (int*)(ws + 389376);      // 2*4608 int
  unsigned char* kg = (unsigned char*)(ws + 426240); // 2*4608 bytes -> 435456
  float4* nbox = (float4*)(ws + 435456);   // 10*1024 float4 -> 599296
  int* nslot   = (int*)(ws + 599296);      // 10*1024 int -> 640256
  int* nmcnt   = (int*)(ws + 640256);      // 10 int -> 640320 (padded)
  u64* maskg   = (u64*)(ws + 640320);      // 10*1024*16 u64 -> 1951040

  k_init  <<<128, 256, 0, stream>>>(cand, cnt, kg, maskg);
  k_select<<<10, 1024, 0, stream>>>(obj, Tsel);
  k_gather<<<(2*R_TOT + 255)/256, 256, 0, stream>>>(obj, Tsel, cand, cnt);
  k_sortA <<<2, 1024, 0, stream>>>(cand, sidx);
  k_decode<<<(2*NPAD + 255)/256, 256, 0, stream>>>(obj, deltas, anchors, sidx, cand, boxv, scv, meta);
  k_sortB <<<2, 1024, 0, stream>>>(cand, ordA);
  k_nmsprep<<<10, 64, 0, stream>>>(ordA, meta, boxv, nbox, nslot, nmcnt);
  {
    dim3 g(10, 16, 16);
    k_mask<<<g, 64, 0, stream>>>(nbox, nmcnt, maskg);
  }
  k_scan  <<<10, 64, 0, stream>>>(maskg, nmcnt, nslot, kg);
  k_output<<<2, 64, 0, stream>>>(kg, ordA, boxv, scv, out);
}

// Round 3
// 441.429 us; speedup vs baseline: 2.9711x; 2.0713x over previous
//
#include <hip/hip_runtime.h>

typedef unsigned long long u64;
typedef unsigned int u32;

#define R_TOT 159882
#define POST 1000
#define IMG_SZ 800.0f
#define NMS_TH 0.7f
#define BBOX_CLIP 4.135166556742356f

__device__ __forceinline__ float fadd_(float a, float b){ return __fadd_rn(a,b); }
__device__ __forceinline__ float fsub_(float a, float b){ return __fsub_rn(a,b); }
__device__ __forceinline__ float fmul_(float a, float b){ return __fmul_rn(a,b); }

__device__ __forceinline__ int level_of(int r){
  return r < 120000 ? 0 : r < 150000 ? 1 : r < 157500 ? 2 : r < 159375 ? 3 : 4;
}
__device__ __forceinline__ int lvl_len(int l){ const int L[5]={120000,30000,7500,1875,507}; return L[l]; }
__device__ __forceinline__ int lvl_off(int l){ const int L[5]={0,120000,150000,157500,159375}; return L[l]; }
__device__ __forceinline__ int lvl_k(int l){ const int L[5]={1000,1000,1000,1000,507}; return L[l]; }

__device__ __forceinline__ u32 mono_(u32 u){ return (u & 0x80000000u) ? ~u : (u | 0x80000000u); }

// ---------- 1. per-(img,lvl) exact radix-select: 12-bit histogram + LDS refine ----------
__global__ __launch_bounds__(1024) void k_select(const float* __restrict__ obj,
                                                 u64* Tsel, int* cntg, u64* glist){
  int g = blockIdx.x, img = g/5, lvl = g%5;
  int s0 = lvl_off(lvl), n = lvl_len(lvl), k = lvl_k(lvl);
  const float* p = obj + img*R_TOT;
  __shared__ int hist[4096];
  __shared__ u64 Lbuf[4096];
  __shared__ int wsum[16];
  __shared__ int h16[16];
  __shared__ int sh_b, sh_rem, sh_cnt;
  __shared__ u64 sh_pref;
  int tid = threadIdx.x, lane = tid & 63, wid = tid >> 6;
  glist[g*1024 + tid] = ~0ull;                 // pad for per-level sort
  if (tid == 0){ cntg[g] = 0; sh_cnt = 0; }
  for (int b = tid; b < 4096; b += 1024) hist[b] = 0;
  __syncthreads();
  for (int e = tid; e < n; e += 1024){
    u32 mu = mono_(__float_as_uint(p[s0+e]));
    atomicAdd(&hist[(~mu) >> 20], 1);
  }
  __syncthreads();
  // block scan over 4-bin groups to locate bin of the k-th smallest key56
  int part = hist[4*tid] + hist[4*tid+1] + hist[4*tid+2] + hist[4*tid+3];
  int x = part;
  for (int d = 1; d < 64; d <<= 1){ int y = __shfl_up(x, d); if (lane >= d) x += y; }
  if (lane == 63) wsum[wid] = x;
  __syncthreads();
  if (tid < 16){ int v = wsum[tid]; for (int d = 1; d < 16; d <<= 1){ int y = __shfl_up(v, d); if (tid >= d) v += y; } wsum[tid] = v; }
  __syncthreads();
  int incl = x + (wid ? wsum[wid-1] : 0);
  int excl = incl - part;
  if (excl < k && k <= incl){
    int c = excl;
    for (int q = 0; q < 4; q++){ int hb = hist[4*tid+q]; if (c + hb >= k){ sh_b = 4*tid+q; sh_rem = k - c; break; } c += hb; }
  }
  __syncthreads();
  int bstar = sh_b;
  int cb = hist[bstar];
  bool inLds = (cb <= 4096);
  if (inLds){
    for (int e = tid; e < n; e += 1024){
      u32 mu = mono_(__float_as_uint(p[s0+e]));
      if (((~mu) >> 20) == (u32)bstar){
        int pos = atomicAdd(&sh_cnt, 1);
        Lbuf[pos] = (((u64)(~mu)) << 24) | (u32)(s0+e);
      }
    }
  }
  if (tid == 0) sh_pref = ((u64)bstar) << 44;
  __syncthreads();
  for (int shift = 40; shift >= 0; shift -= 4){
    if (tid < 16) h16[tid] = 0;
    __syncthreads();
    u64 pref = sh_pref;
    u64 himask = ~((1ull << (shift+4)) - 1ull);
    if (inLds){
      for (int e = tid; e < cb; e += 1024){
        u64 kk = Lbuf[e];
        if ((kk & himask) == (pref & himask)) atomicAdd(&h16[(int)((kk >> shift) & 15)], 1);
      }
    } else {
      for (int e = tid; e < n; e += 1024){
        u32 mu = mono_(__float_as_uint(p[s0+e]));
        u64 kk = (((u64)(~mu)) << 24) | (u32)(s0+e);
        if ((kk & himask) == (pref & himask)) atomicAdd(&h16[(int)((kk >> shift) & 15)], 1);
      }
    }
    __syncthreads();
    if (tid == 0){
      int r2 = sh_rem, cum = 0, dsel = 0;
      for (int d = 0; d < 16; d++){ int hb = h16[d]; if (cum + hb >= r2){ dsel = d; break; } cum += hb; }
      sh_rem = r2 - cum;
      sh_pref = pref | ((u64)dsel << shift);
    }
    __syncthreads();
  }
  if (tid == 0) Tsel[g] = (((u64)lvl) << 56) | sh_pref;
}

// ---------- 2. gather selected keys per (img,lvl) ----------
__global__ void k_gather(const float* __restrict__ obj, const u64* __restrict__ Tsel,
                         int* cntg, u64* glist){
  int t = blockIdx.x * blockDim.x + threadIdx.x;
  if (t >= 2*R_TOT) return;
  int img = t / R_TOT, r = t - img * R_TOT;
  int lvl = level_of(r);
  u32 mu = mono_(__float_as_uint(obj[t]));
  u64 key56 = (((u64)(~mu)) << 24) | (u32)r;
  u64 key = (((u64)lvl) << 56) | key56;
  if (key <= Tsel[img*5 + lvl]){
    int g = img*5 + lvl;
    int pos = atomicAdd(&cntg[g], 1);
    glist[g*1024 + pos] = key56;
  }
}

// ---------- 3. per-level 1024 bitonic sort -> top_k order ----------
__global__ __launch_bounds__(256) void k_sortL(const u64* __restrict__ glist, u32* sidx){
  __shared__ u64 sh[1024];
  int g = blockIdx.x, tid = threadIdx.x;
  for (int i = tid; i < 1024; i += 256) sh[i] = glist[g*1024 + i];
  for (int k2 = 2; k2 <= 1024; k2 <<= 1){
    for (int j = k2 >> 1; j > 0; j >>= 1){
      __syncthreads();
      for (int i = tid; i < 1024; i += 256){
        int ixj = i ^ j;
        if (ixj > i){
          u64 a = sh[i], b = sh[ixj];
          bool up = (i & k2) == 0;
          if ((a > b) == up){ sh[i] = b; sh[ixj] = a; }
        }
      }
    }
  }
  __syncthreads();
  for (int r = tid; r < 1024; r += 256) sidx[g*1024 + r] = (u32)(sh[r] & 0xFFFFFFu);
}

// ---------- 4. decode + clip + valid + sigmoid + output-sort key ----------
__global__ void k_decode(const float* __restrict__ obj, const float4* __restrict__ deltas,
                         const float4* __restrict__ anchors, const u32* __restrict__ sidx,
                         float4* boxL, float* scoreL, int* validL, u64* okeyL,
                         unsigned char* keptR){
  int t = blockIdx.x * blockDim.x + threadIdx.x;
  if (t >= 10*1024) return;
  int g = t >> 10, r = t & 1023;
  int img = g / 5, lvl = g % 5;
  keptR[t] = 0;
  if (r >= lvl_k(lvl)) return;
  int idx = (int)sidx[t];
  float4 a = anchors[idx];
  float4 d = deltas[img*R_TOT + idx];
  float o = obj[img*R_TOT + idx];
  float wa = fsub_(a.z, a.x), ha = fsub_(a.w, a.y);
  float cxa = fadd_(a.x, fmul_(0.5f, wa)), cya = fadd_(a.y, fmul_(0.5f, ha));
  float dw = fminf(d.z, BBOX_CLIP), dh = fminf(d.w, BBOX_CLIP);
  float cx = fadd_(fmul_(d.x, wa), cxa), cy = fadd_(fmul_(d.y, ha), cya);
  float w  = fmul_(expf(dw), wa),        h  = fmul_(expf(dh), ha);
  float x1 = fsub_(cx, fmul_(0.5f, w)), y1 = fsub_(cy, fmul_(0.5f, h));
  float x2 = fadd_(cx, fmul_(0.5f, w)), y2 = fadd_(cy, fmul_(0.5f, h));
  x1 = fminf(fmaxf(x1, 0.0f), IMG_SZ); y1 = fminf(fmaxf(y1, 0.0f), IMG_SZ);
  x2 = fminf(fmaxf(x2, 0.0f), IMG_SZ); y2 = fminf(fmaxf(y2, 0.0f), IMG_SZ);
  bool valid = (fsub_(x2, x1) >= 1e-3f) && (fsub_(y2, y1) >= 1e-3f);
  float e = expf(-o);
  float sig = __fdiv_rn(1.0f, fadd_(1.0f, e));
  float s = valid ? sig : -1.0f;
  u32 sb = __float_as_uint(s);
  u32 ms = (sb & 0x80000000u) ? ~sb : (sb | 0x80000000u);
  boxL[t] = make_float4(x1, y1, x2, y2);
  scoreL[t] = sig;
  validL[t] = valid ? 1 : 0;
  okeyL[t] = (((u64)(~ms)) << 32) | (u32)(lvl*1000 + r);  // (score desc, concat pos asc)
}

// ---------- 5. compact valid per (img,lvl) in rank order; add 801*lvl offset ----------
__global__ __launch_bounds__(64) void k_prep(const int* __restrict__ validL,
                                             const float4* __restrict__ boxL,
                                             float4* nbox, int* nrank, int* ncnt){
  int g = blockIdx.x, lvl = g % 5, K = lvl_k(lvl);
  int tid = threadIdx.x;
  int cnt = 0;
  float off = (float)lvl * 801.0f;
  for (int base = 0; base < K; base += 64){
    int r = base + tid;
    bool v = false; float4 b = make_float4(0,0,0,0);
    if (r < K && validL[g*1024 + r]){ v = true; b = boxL[g*1024 + r]; }
    u64 mask = __ballot(v);
    int before = __popcll(mask & ((1ull << tid) - 1ull));
    if (v){
      int pos = cnt + before;
      nbox[g*1024 + pos] = make_float4(fadd_(b.x,off), fadd_(b.y,off), fadd_(b.z,off), fadd_(b.w,off));
      nrank[g*1024 + pos] = r;
    }
    cnt += __popcll(mask);
  }
  if (tid == 0) ncnt[g] = cnt;
}

// ---------- 6. pairwise IoU bitmask (writes ALL 16 words per live row; zeros elsewhere) ----------
__global__ __launch_bounds__(64) void k_mask(const float4* __restrict__ nbox,
                                             const int* __restrict__ nmcnt, u64* maskg){
  int g = blockIdx.x, ti = blockIdx.y, tj = blockIdx.z;
  int m = nmcnt[g];
  if (ti*64 >= m) return;
  __shared__ float4 shb[64];
  int t = threadIdx.x;
  int j0 = tj*64;
  if (j0 + t < m) shb[t] = nbox[g*1024 + j0 + t];
  __syncthreads();
  int i = ti*64 + t;
  if (i >= m) return;
  float4 a = nbox[g*1024 + i];
  float areaA = fmul_(fsub_(a.z,a.x), fsub_(a.w,a.y));
  u64 bits = 0;
  int jmax = m - j0; if (jmax > 64) jmax = 64;
  for (int jj = 0; jj < jmax; jj++){
    int j = j0 + jj;
    if (j <= i) continue;
    float4 b = shb[jj];
    float ltx = fmaxf(a.x, b.x), lty = fmaxf(a.y, b.y);
    float rbx = fminf(a.z, b.z), rby = fminf(a.w, b.w);
    float wx = fmaxf(fsub_(rbx, ltx), 0.0f), wy = fmaxf(fsub_(rby, lty), 0.0f);
    float inter = fmul_(wx, wy);
    float areaB = fmul_(fsub_(b.z,b.x), fsub_(b.w,b.y));
    float den = fadd_(fsub_(fadd_(areaA, areaB), inter), 1e-9f);
    if (__fdiv_rn(inter, den) > NMS_TH) bits |= (1ull << jj);
  }
  maskg[(g*1024 + i)*16 + tj] = bits;
}

// ---------- 7. greedy scan: ffs keep-loop per 64-chunk + batched parallel OR ----------
__global__ __launch_bounds__(64) void k_scan(const u64* __restrict__ maskg,
                                             const int* __restrict__ nmcnt,
                                             const int* __restrict__ nrank,
                                             unsigned char* keptR){
  int g = blockIdx.x, lane = threadIdx.x;
  int m = nmcnt[g];
  __shared__ int klist[64];
  u64 remv = 0;                 // lane L (<16) owns suppression word L
  int nch = (m + 63) >> 6;
  for (int c = 0; c < nch; c++){
    int row = c*64 + lane;
    u64 diag = (row < m) ? maskg[(g*1024 + row)*16 + c] : 0;
    int rnk  = (row < m) ? nrank[g*1024 + row] : 0;
    u64 cur = __shfl(remv, c);
    int hi = m - c*64; if (hi > 64) hi = 64;
    u64 range = (hi >= 64) ? ~0ull : ((1ull << hi) - 1ull);
    u64 live = (~cur) & range;
    u64 kept = 0;
    while (live){
      int i = __builtin_ctzll(live);
      kept |= (1ull << i);
      u64 di = __shfl(diag, i);
      live &= ~di;
      live &= ~(1ull << i);
    }
    if (row < m && ((kept >> lane) & 1ull)) keptR[g*1024 + rnk] = 1;
    int nk = __popcll(kept);
    if ((kept >> lane) & 1ull){
      int p = __popcll(kept & ((1ull << lane) - 1ull));
      klist[p] = c*64 + lane;
    }
    __syncthreads();
    u64 acc = 0;
    for (int q = (lane >> 4); q < nk; q += 4)
      acc |= maskg[(g*1024 + klist[q])*16 + (lane & 15)];
    acc |= __shfl_xor(acc, 16);
    acc |= __shfl_xor(acc, 32);
    if (lane < 16) remv |= acc;
    __syncthreads();
  }
}

// ---------- 8. compact kept per level (already score-sorted), 8-run bitonic merge, output ----------
__global__ __launch_bounds__(1024) void k_merge_out(const unsigned char* __restrict__ keptR,
                                                    const u64* __restrict__ okeyL,
                                                    const float4* __restrict__ boxL,
                                                    const float* __restrict__ scoreL,
                                                    float* out){
  int img = blockIdx.x, tid = threadIdx.x, lane = tid & 63, wid = tid >> 6;
  __shared__ u64 S[8192];
  __shared__ int cl[8];
  for (int i = tid; i < 8192; i += 1024) S[i] = ~0ull;
  if (tid < 8) cl[tid] = 0;
  __syncthreads();
  if (wid < 5){
    int l = wid, g = img*5 + l;
    int cnt = 0;
    for (int base = 0; base < 1024; base += 64){
      int r = base + lane;
      bool kp = keptR[g*1024 + r] != 0;
      u64 mask = __ballot(kp);
      int before = __popcll(mask & ((1ull << lane) - 1ull));
      if (kp) S[l*1024 + cnt + before] = okeyL[g*1024 + r];
      cnt += __popcll(mask);
    }
    if (lane == 0) cl[l] = cnt;
  }
  __syncthreads();
  // merge 8 sorted runs of 1024 (pads ~0): reflect stage + bitonic halving
  for (int w = 2048; w <= 8192; w <<= 1){
    for (int i = tid; i < 8192; i += 1024){
      int blk = i & ~(w-1), off = i & (w-1);
      if (off < (w >> 1)){
        int j = blk + (w-1) - off;
        u64 a = S[i], b = S[j];
        if (a > b){ S[i] = b; S[j] = a; }
      }
    }
    for (int j = w >> 2; j > 0; j >>= 1){
      __syncthreads();
      for (int i = tid; i < 8192; i += 1024){
        int ixj = i ^ j;
        if (ixj > i){
          u64 a = S[i], b = S[ixj];
          if (a > b){ S[i] = b; S[ixj] = a; }
        }
      }
    }
    __syncthreads();
  }
  int keptTotal = cl[0] + cl[1] + cl[2] + cl[3] + cl[4];
  int lim = keptTotal < POST ? keptTotal : POST;
  for (int t = tid; t < POST; t += 1024){
    float4 bo = make_float4(0,0,0,0);
    float sc = -1.0f;
    if (t < lim){
      u64 key = S[t];
      int pos = (int)(key & 0xFFFFFFFFull);
      int lvl = pos / 1000, r = pos - lvl*1000;
      int g = img*5 + lvl;
      bo = boxL[g*1024 + r];
      sc = scoreL[g*1024 + r];
    }
    out[img*POST*4 + t*4 + 0] = bo.x;
    out[img*POST*4 + t*4 + 1] = bo.y;
    out[img*POST*4 + t*4 + 2] = bo.z;
    out[img*POST*4 + t*4 + 3] = bo.w;
    out[2*POST*4 + img*POST + t] = sc;
  }
}

extern "C" void kernel_launch(void* const* d_in, const int* in_sizes, int n_in,
                              void* d_out, int out_size, void* d_ws, size_t ws_size,
                              hipStream_t stream){
  (void)in_sizes; (void)n_in; (void)out_size; (void)ws_size;
  const float*  obj     = (const float*)d_in[0];
  const float4* deltas  = (const float4*)d_in[1];
  const float4* anchors = (const float4*)d_in[2];
  float* out = (float*)d_out;
  char* ws = (char*)d_ws;
  u64* Tsel    = (u64*)(ws + 0);          // 10 u64
  int* cntg    = (int*)(ws + 256);        // 10 int
  u64* glist   = (u64*)(ws + 512);        // 10*1024 u64   -> 82432
  u32* sidx    = (u32*)(ws + 82432);      // 10*1024 u32   -> 123392
  float4* boxL = (float4*)(ws + 123392);  // 10*1024 f4    -> 287232
  float* scoreL= (float*)(ws + 287232);   // 10*1024 f32   -> 328192
  int* validL  = (int*)(ws + 328192);     // 10*1024 int   -> 369152
  u64* okeyL   = (u64*)(ws + 369152);     // 10*1024 u64   -> 451072
  float4* nbox = (float4*)(ws + 451072);  // 10*1024 f4    -> 614912
  int* nrank   = (int*)(ws + 614912);     // 10*1024 int   -> 655872
  int* ncnt    = (int*)(ws + 655872);     // 10 int        -> 656128
  unsigned char* keptR = (unsigned char*)(ws + 656128); // 10*1024 -> 666368
  u64* maskg   = (u64*)(ws + 666368);     // 10*1024*16 u64 -> 1977088

  k_select<<<10, 1024, 0, stream>>>(obj, Tsel, cntg, glist);
  k_gather<<<(2*R_TOT + 255)/256, 256, 0, stream>>>(obj, Tsel, cntg, glist);
  k_sortL <<<10, 256, 0, stream>>>(glist, sidx);
  k_decode<<<40, 256, 0, stream>>>(obj, deltas, anchors, sidx, boxL, scoreL, validL, okeyL, keptR);
  k_prep  <<<10, 64, 0, stream>>>(validL, boxL, nbox, nrank, ncnt);
  {
    dim3 gm(10, 16, 16);
    k_mask<<<gm, 64, 0, stream>>>(nbox, ncnt, maskg);
  }
  k_scan  <<<10, 64, 0, stream>>>(maskg, ncnt, nrank, keptR);
  k_merge_out<<<2, 1024, 0, stream>>>(keptR, okeyL, boxL, scoreL, out);
}